// Round 2
// baseline (1543.299 us; speedup 1.0000x reference)
//
#include <hip/hip_runtime.h>

typedef float v2f __attribute__((ext_vector_type(2)));

#define HID 32
#define LOG2E 1.4426950408889634f

#if __has_builtin(__builtin_amdgcn_exp2f)
#define EXP2(x) __builtin_amdgcn_exp2f(x)
#else
#define EXP2(x) exp2f(x)
#endif
#if __has_builtin(__builtin_amdgcn_rcpf)
#define RCP(x) __builtin_amdgcn_rcpf(x)
#else
#define RCP(x) (1.0f / (x))
#endif

// Packed fp32 FMA (1 inst / 2 MACs). "v" constraint = ARCH VGPR only — the
// operands must live in arch VGPRs or the compiler inserts v_accvgpr_read
// bounces (that was R0/R1's hidden cost under the 4-wave reg budget).
#define PKFMA(acc, w, h) \
    asm("v_pk_fma_f32 %0, %1, %2, %0" : "+v"(acc) : "v"(w), "v"(h))

// Keep a loaded value materialized (no remat of const loads into the loop).
#define PIN(x) asm volatile("" : "+v"(x))

// xor-butterfly add within 32-lane groups (each group holds every hidden unit
// exactly once, so both halves converge to the same full sum independently)
#define SWZ_ADD(p, imm) do {                                            \
    int _t = __builtin_amdgcn_ds_swizzle(__float_as_int(p), (imm));     \
    (p) += __int_as_float(_t); } while (0)
#define REDUCE32(p) do {                                                \
    SWZ_ADD(p, 0x041F); SWZ_ADD(p, 0x081F); SWZ_ADD(p, 0x101F);        \
    SWZ_ADD(p, 0x201F); SWZ_ADD(p, 0x401F); } while (0)

// waves_per_eu(3,3): force the allocator to target EXACTLY 3 waves/EU.
// With (3,4) it targeted the max (4 waves = 128-reg unified budget) and split
// 68 arch VGPR + ~60 AGPR, paying ~64-96 v_accvgpr_read per LSTM step to feed
// the "v"-constrained pk_fma asm. 3 waves = 168 arch regs: whole state fits.
__global__ __attribute__((amdgpu_waves_per_eu(3, 3))) __launch_bounds__(256)
void lstm_gatesplit(const float* __restrict__ poses,
                    const float* __restrict__ W_ih,
                    const float* __restrict__ W_hh,
                    const float* __restrict__ W_dense,
                    float* __restrict__ out,
                    int B, int T_enc, int T_dec)
{
    // one element per wave; hx row is wave-private -> NO barriers anywhere
    __shared__ __align__(16) float hx[4][HID];

    const int tid  = threadIdx.x;
    const int lane = tid & 63;
    const int wv   = tid >> 6;          // wave within block (0..3)
    const int k    = lane & 31;         // hidden unit
    const int isH  = lane >> 5;         // 0: rows {k, 64+k}=(i,g); 1: {32+k, 96+k}=(f,o)
    const int el   = blockIdx.x * 4 + wv;

    const int rowA = isH * 32 + k;      // i or f
    const int rowB = rowA + 64;         // g or o

    // ---- persistent weights: 72 floats/lane, pinned resident ----
    const v2f* Wih2 = reinterpret_cast<const v2f*>(W_ih);
    v2f wA0 = Wih2[2 * rowA], wA1 = Wih2[2 * rowA + 1];
    v2f wB0 = Wih2[2 * rowB], wB1 = Wih2[2 * rowB + 1];
    v2f whhA[16], whhB[16];
    {
        const v2f* Whh2 = reinterpret_cast<const v2f*>(W_hh);
        #pragma unroll
        for (int j = 0; j < 16; ++j) {
            whhA[j] = Whh2[rowA * 16 + j];
            whhB[j] = Whh2[rowB * 16 + j];
        }
    }
    float wd1 = W_dense[HID + k];
    float wd2 = W_dense[2 * HID + k];

    #pragma unroll
    for (int j = 0; j < 16; ++j) { PIN(whhA[j]); PIN(whhB[j]); }
    PIN(wA0); PIN(wA1); PIN(wB0); PIN(wB1);
    PIN(wd1); PIN(wd2);

    // branchless activation selectors: rowA is always sigmoid; rowB is
    // tanh (half 0) or sigmoid (half 1): act1 = A1 + B1 * rcp(1 + 2^(S1*a1))
    const float S1 = isH ? -LOG2E : 2.0f * LOG2E;
    const float A1 = isH ? 0.0f : 1.0f;
    const float B1 = isH ? 1.0f : -2.0f;

    v2f h2[16];
    #pragma unroll
    for (int j = 0; j < 16; ++j) h2[j] = (v2f){0.f, 0.f};
    float c = 0.f, hk = 0.f;            // both halves keep identical copies

    const float4* poses4 = reinterpret_cast<const float4*>(poses);
    float4*       out4   = reinterpret_cast<float4*>(out);

    // core step: accumulators arrive preloaded with the x @ W_ih.T part
    auto lstm_core = [&](v2f aA, v2f aB) {
        #pragma unroll
        for (int j = 0; j < 16; ++j) {      // 2 independent pk chains
            PKFMA(aA, whhA[j], h2[j]);
            PKFMA(aB, whhB[j], h2[j]);
        }
        const float a0 = aA.x + aA.y;       // i or f pre-activation
        const float a1 = aB.x + aB.y;       // g or o pre-activation
        const float act0 = RCP(1.0f + EXP2(-LOG2E * a0));          // sigmoid
        const float act1 = fmaf(B1, RCP(1.0f + EXP2(S1 * a1)), A1);
        const float xo0 = __shfl_xor(act0, 32, 64);
        const float xo1 = __shfl_xor(act1, 32, 64);
        const float i_ = isH ? xo0  : act0;
        const float f_ = isH ? act0 : xo0;
        const float g_ = isH ? xo1  : act1;
        const float o_ = isH ? act1 : xo1;
        c = fmaf(f_, c, i_ * g_);
        const float th = fmaf(-2.0f, RCP(1.0f + EXP2((2.0f * LOG2E) * c)), 1.0f);
        hk = o_ * th;                       // identical in lanes k and k+32
        if (!isH) hx[wv][k] = hk;           // exec-masked write, wave-private row
        // broadcast read-back: b128 x8 (rows are 128B -> 16B aligned)
        const float4* hr4 = reinterpret_cast<const float4*>(&hx[wv][0]);
        #pragma unroll
        for (int j = 0; j < 8; ++j) {
            const float4 v = hr4[j];        // ds_read_b128
            h2[2 * j]     = (v2f){v.x, v.y};
            h2[2 * j + 1] = (v2f){v.z, v.w};
        }
    };

    // ---------------- encoder (x prefetched one step ahead) ----------------
    float4 x = poses4[el];                  // wave-uniform address
    for (int t = 0; t < T_enc; ++t) {
        float4 xn = x;
        if (t + 1 < T_enc) xn = poses4[(size_t)(t + 1) * B + el];
        v2f aA = {0.f, 0.f}, aB = {0.f, 0.f};
        const v2f x01 = {x.x, x.y}, x23 = {x.z, x.w};
        PKFMA(aA, wA0, x01); PKFMA(aA, wA1, x23);
        PKFMA(aB, wB0, x01); PKFMA(aB, wB1, x23);
        lstm_core(aA, aB);
        x = xn;
    }
    const v2f p01 = {x.x, x.y};             // poses[-1][:,:2], constant in decode

    float v1 = wd1 * hk, v2 = wd2 * hk;     // vel rows 1,2 (row 0 unused)
    REDUCE32(v1); REDUCE32(v2);

    // decode x-part: p01 contribution is loop-invariant -> hoist (2 pk/step saved)
    v2f baseA = {0.f, 0.f}, baseB = {0.f, 0.f};
    PKFMA(baseA, wA0, p01); PKFMA(baseB, wB0, p01);

    // ---------------- decoder ----------------
    for (int t = 0; t < T_dec; ++t) {
        const float rn = rsqrtf(v1 * v1 + v2 * v2);
        const float cs = v1 * rn, sn = v2 * rn;
        if (lane == 0) out4[(size_t)t * B + el] = make_float4(p01.x, p01.y, cs, sn);
        const v2f cssn = {cs, sn};
        v2f aA = baseA, aB = baseB;
        PKFMA(aA, wA1, cssn); PKFMA(aB, wB1, cssn);
        lstm_core(aA, aB);
        v1 = wd1 * hk; v2 = wd2 * hk;
        REDUCE32(v1); REDUCE32(v2);
    }
}

extern "C" void kernel_launch(void* const* d_in, const int* in_sizes, int n_in,
                              void* d_out, int out_size, void* d_ws, size_t ws_size,
                              hipStream_t stream) {
    const float* poses   = (const float*)d_in[0];
    // d_in[1] = deltas: values unused by the reference decoder (only length matters)
    const float* W_ih    = (const float*)d_in[2];
    const float* W_hh    = (const float*)d_in[3];
    const float* W_dense = (const float*)d_in[4];
    float* out = (float*)d_out;

    const int T_enc = 64;                       // fixed by the reference setup
    const int B     = in_sizes[0] / (T_enc * 4);
    const int T_dec = out_size / (B * 4);       // n_new_poses

    dim3 grid(B / 4), block(256);
    hipLaunchKernelGGL(lstm_gatesplit, grid, block, 0, stream,
                       poses, W_ih, W_hh, W_dense, out, B, T_enc, T_dec);
}

// Round 3
// 1482.553 us; speedup vs baseline: 1.0410x; 1.0410x over previous
//
#include <hip/hip_runtime.h>

typedef float v2f __attribute__((ext_vector_type(2)));

#define HID 32
#define LOG2E 1.4426950408889634f

#if __has_builtin(__builtin_amdgcn_exp2f)
#define EXP2(x) __builtin_amdgcn_exp2f(x)
#else
#define EXP2(x) exp2f(x)
#endif
#if __has_builtin(__builtin_amdgcn_rcpf)
#define RCP(x) __builtin_amdgcn_rcpf(x)
#else
#define RCP(x) (1.0f / (x))
#endif

// Packed fp32 FMA via compiler builtin — NOT inline asm. The old
// asm("v_pk_fma_f32", "v" constraints) forced arch-VGPR-only operands; with
// the weight set parked in AGPRs (68 arch + ~100 acc split at 3 waves/EU),
// every asm FMA needed ~2 v_accvgpr_read bounces -> ~130 junk VALU insts per
// step (the measured 198 vs ~65 declared). Compiler-generated VALU reads
// AGPRs directly (gfx90a+ ACC operand bit) -> bounces vanish.
#if __has_builtin(__builtin_elementwise_fma)
#define PKFMA(acc, w, h) (acc) = __builtin_elementwise_fma((w), (h), (acc))
#else
#define PKFMA(acc, w, h) do {                       \
    (acc).x = fmaf((w).x, (h).x, (acc).x);          \
    (acc).y = fmaf((w).y, (h).y, (acc).y); } while (0)
#endif

// Keep a loaded value materialized once (no remat of const loads into loop).
#define PIN(x) asm volatile("" : "+v"(x))

// xor-butterfly add within 32-lane groups (each group holds every hidden unit
// exactly once, so both halves converge to the same full sum independently)
#define SWZ_ADD(p, imm) do {                                            \
    int _t = __builtin_amdgcn_ds_swizzle(__float_as_int(p), (imm));     \
    (p) += __int_as_float(_t); } while (0)
#define REDUCE32(p) do {                                                \
    SWZ_ADD(p, 0x041F); SWZ_ADD(p, 0x081F); SWZ_ADD(p, 0x101F);        \
    SWZ_ADD(p, 0x201F); SWZ_ADD(p, 0x401F); } while (0)

// waves_per_eu(3,3): 3 waves/EU = 170-reg unified budget; the ~135-float
// state fits as arch-VGPR + AGPR split, which is now free to access.
__global__ __attribute__((amdgpu_waves_per_eu(3, 3))) __launch_bounds__(256)
void lstm_gatesplit(const float* __restrict__ poses,
                    const float* __restrict__ W_ih,
                    const float* __restrict__ W_hh,
                    const float* __restrict__ W_dense,
                    float* __restrict__ out,
                    int B, int T_enc, int T_dec)
{
    // one element per wave; hx row is wave-private -> NO barriers anywhere
    __shared__ __align__(16) float hx[4][HID];

    const int tid  = threadIdx.x;
    const int lane = tid & 63;
    const int wv   = tid >> 6;          // wave within block (0..3)
    const int k    = lane & 31;         // hidden unit
    const int isH  = lane >> 5;         // 0: rows {k, 64+k}=(i,g); 1: {32+k, 96+k}=(f,o)
    const int el   = blockIdx.x * 4 + wv;

    const int rowA = isH * 32 + k;      // i or f
    const int rowB = rowA + 64;         // g or o

    // ---- persistent weights: 72 floats/lane ----
    const v2f* Wih2 = reinterpret_cast<const v2f*>(W_ih);
    v2f wA0 = Wih2[2 * rowA], wA1 = Wih2[2 * rowA + 1];
    v2f wB0 = Wih2[2 * rowB], wB1 = Wih2[2 * rowB + 1];
    v2f whhA[16], whhB[16];
    {
        const v2f* Whh2 = reinterpret_cast<const v2f*>(W_hh);
        #pragma unroll
        for (int j = 0; j < 16; ++j) {
            whhA[j] = Whh2[rowA * 16 + j];
            whhB[j] = Whh2[rowB * 16 + j];
        }
    }
    float wd1 = W_dense[HID + k];
    float wd2 = W_dense[2 * HID + k];

    #pragma unroll
    for (int j = 0; j < 16; ++j) { PIN(whhA[j]); PIN(whhB[j]); }
    PIN(wA0); PIN(wA1); PIN(wB0); PIN(wB1);
    PIN(wd1); PIN(wd2);

    // branchless activation selectors: rowA is always sigmoid; rowB is
    // tanh (half 0) or sigmoid (half 1): act1 = A1 + B1 * rcp(1 + 2^(S1*a1))
    const float S1 = isH ? -LOG2E : 2.0f * LOG2E;
    const float A1 = isH ? 0.0f : 1.0f;
    const float B1 = isH ? 1.0f : -2.0f;

    v2f h2[16];
    #pragma unroll
    for (int j = 0; j < 16; ++j) h2[j] = (v2f){0.f, 0.f};
    float c = 0.f, hk = 0.f;            // both halves keep identical copies

    const float4* poses4 = reinterpret_cast<const float4*>(poses);
    float4*       out4   = reinterpret_cast<float4*>(out);

    // core step: accumulators arrive preloaded with the x @ W_ih.T part
    auto lstm_core = [&](v2f aA, v2f aB) {
        #pragma unroll
        for (int j = 0; j < 16; ++j) {      // 2 independent pk chains
            PKFMA(aA, whhA[j], h2[j]);
            PKFMA(aB, whhB[j], h2[j]);
        }
        const float a0 = aA.x + aA.y;       // i or f pre-activation
        const float a1 = aB.x + aB.y;       // g or o pre-activation
        const float act0 = RCP(1.0f + EXP2(-LOG2E * a0));          // sigmoid
        const float act1 = fmaf(B1, RCP(1.0f + EXP2(S1 * a1)), A1);
        const float xo0 = __shfl_xor(act0, 32, 64);
        const float xo1 = __shfl_xor(act1, 32, 64);
        const float i_ = isH ? xo0  : act0;
        const float f_ = isH ? act0 : xo0;
        const float g_ = isH ? xo1  : act1;
        const float o_ = isH ? act1 : xo1;
        c = fmaf(f_, c, i_ * g_);
        const float th = fmaf(-2.0f, RCP(1.0f + EXP2((2.0f * LOG2E) * c)), 1.0f);
        hk = o_ * th;                       // identical in lanes k and k+32
        if (!isH) hx[wv][k] = hk;           // exec-masked write, wave-private row
        // broadcast read-back: b128 x8 (rows are 128B -> 16B aligned)
        const float4* hr4 = reinterpret_cast<const float4*>(&hx[wv][0]);
        #pragma unroll
        for (int j = 0; j < 8; ++j) {
            const float4 v = hr4[j];        // ds_read_b128
            h2[2 * j]     = (v2f){v.x, v.y};
            h2[2 * j + 1] = (v2f){v.z, v.w};
        }
    };

    // ---------------- encoder (x prefetched one step ahead) ----------------
    float4 x = poses4[el];                  // wave-uniform address
    for (int t = 0; t < T_enc; ++t) {
        float4 xn = x;
        if (t + 1 < T_enc) xn = poses4[(size_t)(t + 1) * B + el];
        v2f aA = {0.f, 0.f}, aB = {0.f, 0.f};
        const v2f x01 = {x.x, x.y}, x23 = {x.z, x.w};
        PKFMA(aA, wA0, x01); PKFMA(aA, wA1, x23);
        PKFMA(aB, wB0, x01); PKFMA(aB, wB1, x23);
        lstm_core(aA, aB);
        x = xn;
    }
    const v2f p01 = {x.x, x.y};             // poses[-1][:,:2], constant in decode

    float v1 = wd1 * hk, v2 = wd2 * hk;     // vel rows 1,2 (row 0 unused)
    REDUCE32(v1); REDUCE32(v2);

    // decode x-part: p01 contribution is loop-invariant -> hoist (2 pk/step saved)
    v2f baseA = {0.f, 0.f}, baseB = {0.f, 0.f};
    PKFMA(baseA, wA0, p01); PKFMA(baseB, wB0, p01);

    // ---------------- decoder ----------------
    for (int t = 0; t < T_dec; ++t) {
        const float rn = rsqrtf(v1 * v1 + v2 * v2);
        const float cs = v1 * rn, sn = v2 * rn;
        if (lane == 0) out4[(size_t)t * B + el] = make_float4(p01.x, p01.y, cs, sn);
        const v2f cssn = {cs, sn};
        v2f aA = baseA, aB = baseB;
        PKFMA(aA, wA1, cssn); PKFMA(aB, wB1, cssn);
        lstm_core(aA, aB);
        v1 = wd1 * hk; v2 = wd2 * hk;
        REDUCE32(v1); REDUCE32(v2);
    }
}

extern "C" void kernel_launch(void* const* d_in, const int* in_sizes, int n_in,
                              void* d_out, int out_size, void* d_ws, size_t ws_size,
                              hipStream_t stream) {
    const float* poses   = (const float*)d_in[0];
    // d_in[1] = deltas: values unused by the reference decoder (only length matters)
    const float* W_ih    = (const float*)d_in[2];
    const float* W_hh    = (const float*)d_in[3];
    const float* W_dense = (const float*)d_in[4];
    float* out = (float*)d_out;

    const int T_enc = 64;                       // fixed by the reference setup
    const int B     = in_sizes[0] / (T_enc * 4);
    const int T_dec = out_size / (B * 4);       // n_new_poses

    dim3 grid(B / 4), block(256);
    hipLaunchKernelGGL(lstm_gatesplit, grid, block, 0, stream,
                       poses, W_ih, W_hh, W_dense, out, B, T_enc, T_dec);
}